// Round 1
// baseline (352.706 us; speedup 1.0000x reference)
//
#include <hip/hip_runtime.h>
#include <hip/hip_bf16.h>

#define N_CLUSTERS 4096
#define NPIX (512 * 512)       // 262144 pixels per batch row
#define NBATCH 256             // 32 * 8

// ---------------------------------------------------------------------------
// Kernel A: integer histogram of mapping -> counts[c] in workspace.
// LDS privatization per block, one global int atomicAdd per nonzero bin.
// Fully deterministic (integer atomics).
// ---------------------------------------------------------------------------
__global__ __launch_bounds__(256) void count_kernel(
    const int* __restrict__ mapping, int* __restrict__ counts) {
  __shared__ int bins[N_CLUSTERS];
  for (int i = threadIdx.x; i < N_CLUSTERS; i += 256) bins[i] = 0;
  __syncthreads();

  const int stride = gridDim.x * 256;
  for (int i = blockIdx.x * 256 + threadIdx.x; i < NPIX; i += stride) {
    atomicAdd(&bins[mapping[i]], 1);
  }
  __syncthreads();

  for (int i = threadIdx.x; i < N_CLUSTERS; i += 256) {
    int v = bins[i];
    if (v) atomicAdd(&counts[i], v);
  }
}

// ---------------------------------------------------------------------------
// Kernel B: one block per batch row. LDS fp32 bins, coalesced float4 stream
// of the row, LDS fp32 atomic scatter, then out = bin / count (single writer
// per output element -> no global float atomics).
// ---------------------------------------------------------------------------
__global__ __launch_bounds__(1024) void mean_kernel(
    const float* __restrict__ data, const int* __restrict__ mapping,
    const int* __restrict__ counts, float* __restrict__ out) {
  __shared__ float bins[N_CLUSTERS];
  const int b = blockIdx.x;

  for (int i = threadIdx.x; i < N_CLUSTERS; i += 1024) bins[i] = 0.0f;
  __syncthreads();

  const float4* __restrict__ drow =
      reinterpret_cast<const float4*>(data + (size_t)b * NPIX);
  const int4* __restrict__ map4 = reinterpret_cast<const int4*>(mapping);

  // 262144/4 = 65536 float4 elements; 1024 threads -> 64 iterations.
  for (int i = threadIdx.x; i < NPIX / 4; i += 1024) {
    float4 v = drow[i];
    int4 m = map4[i];
    __hip_atomic_fetch_add(&bins[m.x], v.x, __ATOMIC_RELAXED,
                           __HIP_MEMORY_SCOPE_WORKGROUP);
    __hip_atomic_fetch_add(&bins[m.y], v.y, __ATOMIC_RELAXED,
                           __HIP_MEMORY_SCOPE_WORKGROUP);
    __hip_atomic_fetch_add(&bins[m.z], v.z, __ATOMIC_RELAXED,
                           __HIP_MEMORY_SCOPE_WORKGROUP);
    __hip_atomic_fetch_add(&bins[m.w], v.w, __ATOMIC_RELAXED,
                           __HIP_MEMORY_SCOPE_WORKGROUP);
  }
  __syncthreads();

  float* __restrict__ orow = out + (size_t)b * N_CLUSTERS;
  for (int c = threadIdx.x; c < N_CLUSTERS; c += 1024) {
    orow[c] = bins[c] / (float)counts[c];
  }
}

extern "C" void kernel_launch(void* const* d_in, const int* in_sizes, int n_in,
                              void* d_out, int out_size, void* d_ws, size_t ws_size,
                              hipStream_t stream) {
  const float* data = (const float*)d_in[0];   // [256][262144] fp32
  const int* mapping = (const int*)d_in[1];    // [262144] int32
  float* out = (float*)d_out;                  // [256][4096] fp32
  int* counts = (int*)d_ws;                    // [4096] int32 scratch

  // Zero the counts accumulator every launch (ws is poisoned, and we atomic
  // into it). hipMemsetAsync is graph-capture safe.
  hipMemsetAsync(counts, 0, N_CLUSTERS * sizeof(int), stream);

  count_kernel<<<256, 256, 0, stream>>>(mapping, counts);
  mean_kernel<<<NBATCH, 1024, 0, stream>>>(data, mapping, counts, out);
}

// Round 2
// 220.234 us; speedup vs baseline: 1.6015x; 1.6015x over previous
//
#include <hip/hip_runtime.h>
#include <hip/hip_bf16.h>

#define N_PIX (512 * 512)   // 262144 pixels
#define N_CLU 4096
#define N_ROW 256           // 32*8 batch rows
#define CHUNK 1024
#define NCHUNK (N_PIX / CHUNK)  // 256

// ===========================================================================
// Tier 1/2 shared: deterministic counting sort of pixels by cluster.
// ===========================================================================

// K1: per-chunk histogram. hist[ch][c] = #pixels of cluster c in chunk ch.
__global__ __launch_bounds__(256) void k_hist(const int* __restrict__ map,
                                              int* __restrict__ hist) {
  __shared__ int h[N_CLU];
  for (int i = threadIdx.x; i < N_CLU; i += 256) h[i] = 0;
  __syncthreads();
  const int4 m4 =
      reinterpret_cast<const int4*>(map)[blockIdx.x * 256 + threadIdx.x];
  atomicAdd(&h[m4.x], 1);
  atomicAdd(&h[m4.y], 1);
  atomicAdd(&h[m4.z], 1);
  atomicAdd(&h[m4.w], 1);
  __syncthreads();
  int* o = hist + blockIdx.x * N_CLU;
  for (int i = threadIdx.x; i < N_CLU; i += 256) o[i] = h[i];
}

// K2: in-place exclusive scan of hist over the chunk axis, per cluster.
// grid 64 x 256: block owns 64 clusters; 4 threads per cluster scan quarters.
__global__ __launch_bounds__(256) void k_scan_chunks(int* __restrict__ hist,
                                                     int* __restrict__ counts) {
  __shared__ int qsum[4][64];
  const int cl = threadIdx.x & 63;
  const int q = threadIdx.x >> 6;            // 0..3, chunks [q*64, q*64+64)
  const int c = blockIdx.x * 64 + cl;
  int s = 0;
#pragma unroll 8
  for (int ch = q * 64; ch < q * 64 + 64; ++ch) s += hist[ch * N_CLU + c];
  qsum[q][cl] = s;
  __syncthreads();
  int qb = 0;
  for (int j = 0; j < 4; ++j) qb += (j < q) ? qsum[j][cl] : 0;
  if (q == 3) counts[c] = qb + s;
  int run = qb;
#pragma unroll 4
  for (int ch = q * 64; ch < q * 64 + 64; ++ch) {
    int v = hist[ch * N_CLU + c];
    hist[ch * N_CLU + c] = run;
    run += v;
  }
}

// K2b: exclusive scan of counts[4096] -> base[4096]. Single block.
__global__ __launch_bounds__(256) void k_scan_base(const int* __restrict__ counts,
                                                   int* __restrict__ base) {
  __shared__ int part[256];
  const int t = threadIdx.x;
  int loc[16];
  int s = 0;
#pragma unroll
  for (int j = 0; j < 16; ++j) {
    loc[j] = s;
    s += counts[t * 16 + j];
  }
  part[t] = s;
  __syncthreads();
  if (t == 0) {
    int r = 0;
    for (int i = 0; i < 256; ++i) {
      int v = part[i];
      part[i] = r;
      r += v;
    }
  }
  __syncthreads();
  const int b = part[t];
#pragma unroll
  for (int j = 0; j < 16; ++j) base[t * 16 + j] = b + loc[j];
}

// K3: stable scatter. One wave per chunk; intra-group stable rank via 64-lane
// broadcast loop (deterministic, no atomics).
__global__ __launch_bounds__(64) void k_scatter(const int* __restrict__ map,
                                                const int* __restrict__ hist,
                                                const int* __restrict__ base,
                                                int* __restrict__ perm,
                                                int* __restrict__ rank) {
  __shared__ int off[N_CLU];
  const int ch = blockIdx.x;
  const int lane = threadIdx.x;
  for (int i = lane; i < N_CLU; i += 64) off[i] = base[i] + hist[ch * N_CLU + i];
  __syncthreads();
  for (int g = 0; g < CHUNK / 64; ++g) {
    const int p = ch * CHUNK + g * 64 + lane;
    const int c = map[p];
    int r = 0, cnt = 0;
    for (int k = 0; k < 64; ++k) {
      const int ck = __shfl(c, k, 64);
      cnt += (ck == c) ? 1 : 0;
      r += ((ck == c) && (k < lane)) ? 1 : 0;
    }
    const int pos = off[c] + r;
    perm[pos] = p;
    rank[p] = pos;
    __syncthreads();
    if (r == cnt - 1) off[c] = pos + 1;  // last occurrence bumps the cursor
    __syncthreads();
  }
}

// ===========================================================================
// Tier 1: physical reorder into transposed-sorted layout + clean reduce.
// ===========================================================================

// K4: sortedT[rank[p]][b] = data[b][p]. Tile 64 px x 64 rows via LDS.
// grid = (N_PIX/64) * 4 row-chunks = 16384 blocks x 256 threads.
__global__ __launch_bounds__(256) void k_reorder(const float* __restrict__ data,
                                                 const int* __restrict__ rank,
                                                 float* __restrict__ sortedT) {
  __shared__ float tile[64][65];  // [px][row], pad -> conflict-free both ways
  const int pxt = blockIdx.x >> 2;
  const int rc = blockIdx.x & 3;
  const int p0 = pxt * 64;
  const int b0 = rc * 64;
  const int t = threadIdx.x;

  // Stage A: coalesced scalar reads (wave = 256B contiguous per row).
  const int px = t & 63;
  const int r0 = t >> 6;  // 0..3
#pragma unroll
  for (int k = 0; k < 16; ++k) {
    const int row = r0 + k * 4;
    tile[px][row] = data[(size_t)(b0 + row) * N_PIX + p0 + px];
  }
  __syncthreads();

  // Stage B: per pixel, write a contiguous 256B row-chunk (16 lanes x float4).
  const int rowg = t & 15;  // rows 4*rowg..4*rowg+3
  const int pxs = t >> 4;   // 0..15
#pragma unroll
  for (int it = 0; it < 4; ++it) {
    const int px2 = pxs + 16 * it;
    const int rk = rank[p0 + px2];
    float4 v;
    v.x = tile[px2][4 * rowg + 0];
    v.y = tile[px2][4 * rowg + 1];
    v.z = tile[px2][4 * rowg + 2];
    v.w = tile[px2][4 * rowg + 3];
    *reinterpret_cast<float4*>(sortedT + (size_t)rk * N_ROW + b0 + 4 * rowg) = v;
  }
}

// K5T: one block per cluster; stream contiguous pixel-vectors, accumulate in
// registers, reduce 4 waves via LDS, scatter 4B stores to out[b][c].
__global__ __launch_bounds__(256) void k_meanT(const float* __restrict__ sortedT,
                                               const int* __restrict__ base,
                                               const int* __restrict__ counts,
                                               float* __restrict__ out) {
  __shared__ float4 red[3][64];
  const int c = blockIdx.x;
  const int t = threadIdx.x;
  const int r4 = t & 63;  // float4 index over rows
  const int w = t >> 6;
  const int bs = base[c];
  const int cnt = counts[c];
  float4 acc = {0.f, 0.f, 0.f, 0.f};
  for (int i = w; i < cnt; i += 4) {
    const float4 v = *reinterpret_cast<const float4*>(
        sortedT + (size_t)(bs + i) * N_ROW + r4 * 4);
    acc.x += v.x;
    acc.y += v.y;
    acc.z += v.z;
    acc.w += v.w;
  }
  if (w > 0) red[w - 1][r4] = acc;
  __syncthreads();
  if (w == 0) {
#pragma unroll
    for (int j = 0; j < 3; ++j) {
      const float4 v = red[j][r4];
      acc.x += v.x;
      acc.y += v.y;
      acc.z += v.z;
      acc.w += v.w;
    }
    const float fc = (float)cnt;
    out[(size_t)(4 * r4 + 0) * N_CLU + c] = cnt ? acc.x / fc : 0.f;
    out[(size_t)(4 * r4 + 1) * N_CLU + c] = cnt ? acc.y / fc : 0.f;
    out[(size_t)(4 * r4 + 2) * N_CLU + c] = cnt ? acc.z / fc : 0.f;
    out[(size_t)(4 * r4 + 3) * N_CLU + c] = cnt ? acc.w / fc : 0.f;
  }
}

// ===========================================================================
// Tier 2: no room for sortedT — gather directly (column loads), still no
// atomics. Block = cluster, thread = batch row.
// ===========================================================================
__global__ __launch_bounds__(256) void k_mean_gather(
    const float* __restrict__ data, const int* __restrict__ perm,
    const int* __restrict__ base, const int* __restrict__ counts,
    float* __restrict__ out) {
  const int c = blockIdx.x;
  const int row = threadIdx.x;
  const int bs = base[c];
  const int cnt = counts[c];
  float acc = 0.f;
  for (int i = 0; i < cnt; ++i) {
    const int p = perm[bs + i];
    acc += data[(size_t)row * N_PIX + p];
  }
  out[(size_t)row * N_CLU + c] = cnt ? acc / (float)cnt : 0.f;
}

// ===========================================================================
// Tier 3: round-1 LDS-atomic fallback (minimal ws).
// ===========================================================================
__global__ __launch_bounds__(256) void count_kernel(const int* __restrict__ mapping,
                                                    int* __restrict__ counts) {
  __shared__ int bins[N_CLU];
  for (int i = threadIdx.x; i < N_CLU; i += 256) bins[i] = 0;
  __syncthreads();
  const int stride = gridDim.x * 256;
  for (int i = blockIdx.x * 256 + threadIdx.x; i < N_PIX; i += stride)
    atomicAdd(&bins[mapping[i]], 1);
  __syncthreads();
  for (int i = threadIdx.x; i < N_CLU; i += 256) {
    int v = bins[i];
    if (v) atomicAdd(&counts[i], v);
  }
}

__global__ __launch_bounds__(1024) void mean_kernel(
    const float* __restrict__ data, const int* __restrict__ mapping,
    const int* __restrict__ counts, float* __restrict__ out) {
  __shared__ float bins[N_CLU];
  const int b = blockIdx.x;
  for (int i = threadIdx.x; i < N_CLU; i += 1024) bins[i] = 0.0f;
  __syncthreads();
  const float4* drow = reinterpret_cast<const float4*>(data + (size_t)b * N_PIX);
  const int4* map4 = reinterpret_cast<const int4*>(mapping);
  for (int i = threadIdx.x; i < N_PIX / 4; i += 1024) {
    float4 v = drow[i];
    int4 m = map4[i];
    __hip_atomic_fetch_add(&bins[m.x], v.x, __ATOMIC_RELAXED, __HIP_MEMORY_SCOPE_WORKGROUP);
    __hip_atomic_fetch_add(&bins[m.y], v.y, __ATOMIC_RELAXED, __HIP_MEMORY_SCOPE_WORKGROUP);
    __hip_atomic_fetch_add(&bins[m.z], v.z, __ATOMIC_RELAXED, __HIP_MEMORY_SCOPE_WORKGROUP);
    __hip_atomic_fetch_add(&bins[m.w], v.w, __ATOMIC_RELAXED, __HIP_MEMORY_SCOPE_WORKGROUP);
  }
  __syncthreads();
  float* orow = out + (size_t)b * N_CLU;
  for (int c = threadIdx.x; c < N_CLU; c += 1024)
    orow[c] = bins[c] / (float)counts[c];
}

// ===========================================================================
extern "C" void kernel_launch(void* const* d_in, const int* in_sizes, int n_in,
                              void* d_out, int out_size, void* d_ws, size_t ws_size,
                              hipStream_t stream) {
  const float* data = (const float*)d_in[0];   // [256][262144] fp32
  const int* mapping = (const int*)d_in[1];    // [262144] int32
  float* out = (float*)d_out;                  // [256][4096] fp32
  char* ws = (char*)d_ws;

  const size_t OFF_HIST = 0;
  const size_t OFF_BASE = (size_t)NCHUNK * N_CLU * 4;        // 4 MiB
  const size_t OFF_CNT = OFF_BASE + (size_t)N_CLU * 4;
  const size_t OFF_PERM = OFF_CNT + (size_t)N_CLU * 4;
  const size_t OFF_RANK = OFF_PERM + (size_t)N_PIX * 4;
  const size_t OFF_SORT = OFF_RANK + (size_t)N_PIX * 4;      // 6,324,224
  const size_t NEED_SORT = OFF_SORT + (size_t)N_PIX * N_ROW * 4;  // ~275 MB

  if (ws_size >= OFF_SORT) {
    int* hist = (int*)(ws + OFF_HIST);
    int* base = (int*)(ws + OFF_BASE);
    int* counts = (int*)(ws + OFF_CNT);
    int* perm = (int*)(ws + OFF_PERM);
    int* rank = (int*)(ws + OFF_RANK);

    k_hist<<<NCHUNK, 256, 0, stream>>>(mapping, hist);
    k_scan_chunks<<<N_CLU / 64, 256, 0, stream>>>(hist, counts);
    k_scan_base<<<1, 256, 0, stream>>>(counts, base);
    k_scatter<<<NCHUNK, 64, 0, stream>>>(mapping, hist, base, perm, rank);

    if (ws_size >= NEED_SORT) {
      float* sortedT = (float*)(ws + OFF_SORT);
      k_reorder<<<(N_PIX / 64) * 4, 256, 0, stream>>>(data, rank, sortedT);
      k_meanT<<<N_CLU, 256, 0, stream>>>(sortedT, base, counts, out);
    } else {
      k_mean_gather<<<N_CLU, 256, 0, stream>>>(data, perm, base, counts, out);
    }
  } else {
    int* counts = (int*)ws;
    hipMemsetAsync(counts, 0, N_CLU * sizeof(int), stream);
    count_kernel<<<256, 256, 0, stream>>>(mapping, counts);
    mean_kernel<<<N_ROW, 1024, 0, stream>>>(data, mapping, counts, out);
  }
}

// Round 4
// 148.136 us; speedup vs baseline: 2.3810x; 1.4867x over previous
//
#include <hip/hip_runtime.h>
#include <hip/hip_bf16.h>
#include <hip/hip_fp16.h>

#define N_PIX (512 * 512)   // 262144 pixels
#define N_CLU 4096
#define N_ROW 256           // 32*8 batch rows
#define CHUNK 1024
#define NCHUNK (N_PIX / CHUNK)  // 256

typedef unsigned int u32;
typedef unsigned short u16;
typedef float f32x4 __attribute__((ext_vector_type(4)));

// ===========================================================================
// Deterministic counting sort of pixels by cluster (rank only).
// ===========================================================================

// K1: per-chunk histogram. hist[ch][c] = #pixels of cluster c in chunk ch.
__global__ __launch_bounds__(256) void k_hist(const int* __restrict__ map,
                                              int* __restrict__ hist) {
  __shared__ int h[N_CLU];
  for (int i = threadIdx.x; i < N_CLU; i += 256) h[i] = 0;
  __syncthreads();
  const int4 m4 =
      reinterpret_cast<const int4*>(map)[blockIdx.x * 256 + threadIdx.x];
  atomicAdd(&h[m4.x], 1);
  atomicAdd(&h[m4.y], 1);
  atomicAdd(&h[m4.z], 1);
  atomicAdd(&h[m4.w], 1);
  __syncthreads();
  int* o = hist + blockIdx.x * N_CLU;
  for (int i = threadIdx.x; i < N_CLU; i += 256) o[i] = h[i];
}

// K2: in-place exclusive scan of hist over the chunk axis, per cluster.
__global__ __launch_bounds__(256) void k_scan_chunks(int* __restrict__ hist,
                                                     int* __restrict__ counts) {
  __shared__ int qsum[4][64];
  const int cl = threadIdx.x & 63;
  const int q = threadIdx.x >> 6;            // 0..3, chunks [q*64, q*64+64)
  const int c = blockIdx.x * 64 + cl;
  int s = 0;
#pragma unroll 8
  for (int ch = q * 64; ch < q * 64 + 64; ++ch) s += hist[ch * N_CLU + c];
  qsum[q][cl] = s;
  __syncthreads();
  int qb = 0;
  for (int j = 0; j < 4; ++j) qb += (j < q) ? qsum[j][cl] : 0;
  if (q == 3) counts[c] = qb + s;
  int run = qb;
#pragma unroll 4
  for (int ch = q * 64; ch < q * 64 + 64; ++ch) {
    int v = hist[ch * N_CLU + c];
    hist[ch * N_CLU + c] = run;
    run += v;
  }
}

// K2b: exclusive scan of counts[4096] -> base[4096]. Single block.
__global__ __launch_bounds__(256) void k_scan_base(const int* __restrict__ counts,
                                                   int* __restrict__ base) {
  __shared__ int part[256];
  const int t = threadIdx.x;
  int loc[16];
  int s = 0;
#pragma unroll
  for (int j = 0; j < 16; ++j) {
    loc[j] = s;
    s += counts[t * 16 + j];
  }
  part[t] = s;
  __syncthreads();
  if (t == 0) {
    int r = 0;
    for (int i = 0; i < 256; ++i) {
      int v = part[i];
      part[i] = r;
      r += v;
    }
  }
  __syncthreads();
  const int b = part[t];
#pragma unroll
  for (int j = 0; j < 16; ++j) base[t * 16 + j] = b + loc[j];
}

// K3: stable scatter -> rank[p] = sorted position of pixel p.
__global__ __launch_bounds__(64) void k_scatter(const int* __restrict__ map,
                                                const int* __restrict__ hist,
                                                const int* __restrict__ base,
                                                int* __restrict__ rank) {
  __shared__ int off[N_CLU];
  const int ch = blockIdx.x;
  const int lane = threadIdx.x;
  for (int i = lane; i < N_CLU; i += 64) off[i] = base[i] + hist[ch * N_CLU + i];
  __syncthreads();
  for (int g = 0; g < CHUNK / 64; ++g) {
    const int p = ch * CHUNK + g * 64 + lane;
    const int c = map[p];
    int r = 0, cnt = 0;
    for (int k = 0; k < 64; ++k) {
      const int ck = __shfl(c, k, 64);
      cnt += (ck == c) ? 1 : 0;
      r += ((ck == c) && (k < lane)) ? 1 : 0;
    }
    const int pos = off[c] + r;
    rank[p] = pos;
    __syncthreads();
    if (r == cnt - 1) off[c] = pos + 1;  // last occurrence bumps the cursor
    __syncthreads();
  }
}

// ===========================================================================
// K4: sorted transpose to fp16. sortedT[rank[p]] = fp16(data[:, p]) as a
// contiguous 512B row-vector (256 rows x 2B). Tile: 64 px x 256 rows.
// ===========================================================================
__global__ __launch_bounds__(256) void k_transpose_sorted(
    const float* __restrict__ data, const int* __restrict__ rank,
    uint4* __restrict__ sortedT) {
  __shared__ u16 tile[64][258];  // row stride 516B -> stage-A writes ~free
  const int p0 = blockIdx.x * 64;
  const int t = threadIdx.x;

  // Stage A: coalesced float4 reads (wave = 1KiB contiguous), fp16 to LDS.
  const int lane4 = t & 15;  // which float4 of the 64-px row segment
  const int rowA = t >> 4;   // 0..15
  const f32x4* d4 = reinterpret_cast<const f32x4*>(data);
#pragma unroll
  for (int k = 0; k < 16; ++k) {
    const int row = rowA + k * 16;
    const f32x4 v = __builtin_nontemporal_load(
        d4 + (size_t)row * (N_PIX / 4) + (p0 >> 2) + lane4);
    const int px = lane4 * 4;
    tile[px + 0][row] = __half_as_ushort(__float2half(v.x));
    tile[px + 1][row] = __half_as_ushort(__float2half(v.y));
    tile[px + 2][row] = __half_as_ushort(__float2half(v.z));
    tile[px + 3][row] = __half_as_ushort(__float2half(v.w));
  }
  __syncthreads();

  // Stage B: per pixel, one contiguous 512B vector write (32 lanes x 16B).
  const int chunk = t & 31;  // 16B chunk (8 rows) of the vector
  const int pxs = t >> 5;    // 0..7
#pragma unroll
  for (int it = 0; it < 8; ++it) {
    const int px2 = pxs + 8 * it;
    const int rk = rank[p0 + px2];
    const u32* src = reinterpret_cast<const u32*>(&tile[px2][chunk * 8]);
    uint4 v;
    v.x = src[0];
    v.y = src[1];
    v.z = src[2];
    v.w = src[3];
    sortedT[(size_t)rk * 32 + chunk] = v;
  }
}

// ===========================================================================
// K5: reduce. Block per cluster (XCD-swizzled); stream contiguous 512B
// pixel-vectors, accumulate fp32 in registers, LDS tree over 8 groups.
// ===========================================================================
__global__ __launch_bounds__(256) void k_reduce(const uint4* __restrict__ sortedT,
                                                const int* __restrict__ base,
                                                const int* __restrict__ counts,
                                                float* __restrict__ out) {
  __shared__ float red[8][256];
  const int bid = blockIdx.x;
  const int c = ((bid & 7) << 9) | (bid >> 3);  // 4096 = 8 XCDs x 512
  const int t = threadIdx.x;
  const int chunk = t & 31;  // rows chunk*8 .. chunk*8+7
  const int g = t >> 5;      // 0..7 pixel interleave
  const int bs = base[c];
  const int cnt = counts[c];
  float acc[8] = {0.f, 0.f, 0.f, 0.f, 0.f, 0.f, 0.f, 0.f};
  for (int i = g; i < cnt; i += 8) {
    const uint4 v = sortedT[(size_t)(bs + i) * 32 + chunk];
    const float2 f0 = __half22float2(*reinterpret_cast<const __half2*>(&v.x));
    const float2 f1 = __half22float2(*reinterpret_cast<const __half2*>(&v.y));
    const float2 f2 = __half22float2(*reinterpret_cast<const __half2*>(&v.z));
    const float2 f3 = __half22float2(*reinterpret_cast<const __half2*>(&v.w));
    acc[0] += f0.x;
    acc[1] += f0.y;
    acc[2] += f1.x;
    acc[3] += f1.y;
    acc[4] += f2.x;
    acc[5] += f2.y;
    acc[6] += f3.x;
    acc[7] += f3.y;
  }
#pragma unroll
  for (int j = 0; j < 8; ++j) red[g][chunk * 8 + j] = acc[j];
  __syncthreads();
  const float inv = cnt ? 1.0f / (float)cnt : 0.0f;
  float s = 0.f;
#pragma unroll
  for (int j = 0; j < 8; ++j) s += red[j][t];
  out[(size_t)t * N_CLU + c] = s * inv;  // row = t
}

// ===========================================================================
// Tier-3 fallback (tiny ws): round-1 LDS-atomic version.
// ===========================================================================
__global__ __launch_bounds__(256) void count_kernel(const int* __restrict__ mapping,
                                                    int* __restrict__ counts) {
  __shared__ int bins[N_CLU];
  for (int i = threadIdx.x; i < N_CLU; i += 256) bins[i] = 0;
  __syncthreads();
  const int stride = gridDim.x * 256;
  for (int i = blockIdx.x * 256 + threadIdx.x; i < N_PIX; i += stride)
    atomicAdd(&bins[mapping[i]], 1);
  __syncthreads();
  for (int i = threadIdx.x; i < N_CLU; i += 256) {
    int v = bins[i];
    if (v) atomicAdd(&counts[i], v);
  }
}

__global__ __launch_bounds__(1024) void mean_kernel(
    const float* __restrict__ data, const int* __restrict__ mapping,
    const int* __restrict__ counts, float* __restrict__ out) {
  __shared__ float bins[N_CLU];
  const int b = blockIdx.x;
  for (int i = threadIdx.x; i < N_CLU; i += 1024) bins[i] = 0.0f;
  __syncthreads();
  const float4* drow = reinterpret_cast<const float4*>(data + (size_t)b * N_PIX);
  const int4* map4 = reinterpret_cast<const int4*>(mapping);
  for (int i = threadIdx.x; i < N_PIX / 4; i += 1024) {
    float4 v = drow[i];
    int4 m = map4[i];
    __hip_atomic_fetch_add(&bins[m.x], v.x, __ATOMIC_RELAXED, __HIP_MEMORY_SCOPE_WORKGROUP);
    __hip_atomic_fetch_add(&bins[m.y], v.y, __ATOMIC_RELAXED, __HIP_MEMORY_SCOPE_WORKGROUP);
    __hip_atomic_fetch_add(&bins[m.z], v.z, __ATOMIC_RELAXED, __HIP_MEMORY_SCOPE_WORKGROUP);
    __hip_atomic_fetch_add(&bins[m.w], v.w, __ATOMIC_RELAXED, __HIP_MEMORY_SCOPE_WORKGROUP);
  }
  __syncthreads();
  float* orow = out + (size_t)b * N_CLU;
  for (int c = threadIdx.x; c < N_CLU; c += 1024)
    orow[c] = bins[c] / (float)counts[c];
}

// ===========================================================================
extern "C" void kernel_launch(void* const* d_in, const int* in_sizes, int n_in,
                              void* d_out, int out_size, void* d_ws, size_t ws_size,
                              hipStream_t stream) {
  const float* data = (const float*)d_in[0];   // [256][262144] fp32
  const int* mapping = (const int*)d_in[1];    // [262144] int32
  float* out = (float*)d_out;                  // [256][4096] fp32
  char* ws = (char*)d_ws;

  const size_t OFF_HIST = 0;
  const size_t OFF_BASE = (size_t)NCHUNK * N_CLU * 4;          // 4 MiB
  const size_t OFF_CNT = OFF_BASE + (size_t)N_CLU * 4;
  const size_t OFF_RANK = OFF_CNT + (size_t)N_CLU * 4;
  const size_t OFF_SORT = OFF_RANK + (size_t)N_PIX * 4;        // 16B-aligned
  const size_t NEED = OFF_SORT + (size_t)N_PIX * N_ROW * 2;    // ~133 MiB

  if (ws_size >= NEED) {
    int* hist = (int*)(ws + OFF_HIST);
    int* base = (int*)(ws + OFF_BASE);
    int* counts = (int*)(ws + OFF_CNT);
    int* rank = (int*)(ws + OFF_RANK);
    uint4* sortedT = (uint4*)(ws + OFF_SORT);

    k_hist<<<NCHUNK, 256, 0, stream>>>(mapping, hist);
    k_scan_chunks<<<N_CLU / 64, 256, 0, stream>>>(hist, counts);
    k_scan_base<<<1, 256, 0, stream>>>(counts, base);
    k_scatter<<<NCHUNK, 64, 0, stream>>>(mapping, hist, base, rank);
    k_transpose_sorted<<<N_PIX / 64, 256, 0, stream>>>(data, rank, sortedT);
    k_reduce<<<N_CLU, 256, 0, stream>>>(sortedT, base, counts, out);
  } else {
    int* counts = (int*)ws;
    (void)hipMemsetAsync(counts, 0, N_CLU * sizeof(int), stream);
    count_kernel<<<256, 256, 0, stream>>>(mapping, counts);
    mean_kernel<<<N_ROW, 1024, 0, stream>>>(data, mapping, counts, out);
  }
}